// Round 1
// baseline (1760.466 us; speedup 1.0000x reference)
//
#include <hip/hip_runtime.h>
#include <hip/hip_bf16.h>
#include <math.h>

typedef __bf16 bf16_t;
typedef __attribute__((ext_vector_type(8))) __bf16 bf16x8;
typedef __attribute__((ext_vector_type(4))) __bf16 bf16x4;
typedef __attribute__((ext_vector_type(4))) float f32x4;

#define T_TOK 100352      // 32 * 3136 tokens (= Bw*N = 2048*49)
#define DIMC 256
#define HEADS 8
#define HD 32
#define WS7 7
#define NTOK 49
#define SHIFT3 3
#define HH 56
#define SCALE_QK 0.17677669529663687f

// window-token row -> x row (shift maps source and dest to the SAME x row)
__device__ __forceinline__ int xrow_of(int rr) {
    int wi = rr / 49; int t = rr - wi * 49;
    int b = wi >> 6; int w64 = wi & 63;
    int wh = w64 >> 3, ww = w64 & 7;
    int i = t / 7, j = t - i * 7;
    int hy = wh * 7 + i, wy = ww * 7 + j;
    int hx = hy + SHIFT3; if (hx >= HH) hx -= HH;
    int wx = wy + SHIFT3; if (wx >= HH) wx -= HH;
    return b * (HH * HH) + hx * HH + wx;
}

// ---------------- weight transpose + bf16 cast:  W[K][Nc] -> WT[Nc][K] ----------------
__global__ __launch_bounds__(256) void transpose_cast(const float* __restrict__ W,
                                                      bf16_t* __restrict__ WT,
                                                      int K, int Nc) {
    int t = blockIdx.x * 256 + threadIdx.x;      // grid sized exactly K*Nc/256
    int k = t / Nc, c = t - k * Nc;
    WT[(size_t)c * K + k] = (bf16_t)W[t];
}

// ---------------- LayerNorm (+optional window gather) + bf16 cast ----------------
// MAP=1: out row r gathers from x row xrow_of(r) (LN1 + shift + partition)
// MAP=0: identity rows (LN2)
template <int MAP>
__global__ __launch_bounds__(256) void ln_kernel(const float* __restrict__ x,
                                                 const float* __restrict__ g,
                                                 const float* __restrict__ bsh,
                                                 bf16_t* __restrict__ out) {
    int wv = threadIdx.x >> 6, l = threadIdx.x & 63;
    int r = blockIdx.x * 4 + wv;
    int xr = MAP ? xrow_of(r) : r;
    float4 v = ((const float4*)(x + (size_t)xr * DIMC))[l];
    float s = v.x + v.y + v.z + v.w;
    float sq = v.x * v.x + v.y * v.y + v.z * v.z + v.w * v.w;
    #pragma unroll
    for (int off = 32; off; off >>= 1) {
        s += __shfl_down(s, off);
        sq += __shfl_down(sq, off);
    }
    s = __shfl(s, 0); sq = __shfl(sq, 0);
    float mean = s * (1.f / 256.f);
    float var = sq * (1.f / 256.f) - mean * mean;
    float rstd = rsqrtf(var + 1e-5f);
    float4 gv = ((const float4*)g)[l];
    float4 bv = ((const float4*)bsh)[l];
    bf16x4 o;
    o[0] = (bf16_t)((v.x - mean) * rstd * gv.x + bv.x);
    o[1] = (bf16_t)((v.y - mean) * rstd * gv.y + bv.y);
    o[2] = (bf16_t)((v.z - mean) * rstd * gv.z + bv.z);
    o[3] = (bf16_t)((v.w - mean) * rstd * gv.w + bv.w);
    *(bf16x4*)(out + (size_t)r * DIMC + l * 4) = o;
}

// ---------------- bf16 MFMA GEMM: C[M][Nc] = A[M][K] * BT[Nc][K]^T + bias ----------------
// Block: 256 thr (4 waves), tile 64x64, each wave does 16 rows x 64 cols.
// EPI: 0 = bias, store bf16 | 1 = bias+gelu, bf16 | 2 = bias + resid[r], f32 |
//      3 = bias + scatter to xrow_of(r) with resid, f32
template <int EPI>
__global__ __launch_bounds__(256) void gemm_kernel(const bf16_t* __restrict__ A,
                                                   const bf16_t* __restrict__ BT,
                                                   const float* __restrict__ bias,
                                                   int Nc, int K,
                                                   bf16_t* __restrict__ outb,
                                                   float* __restrict__ outf,
                                                   const float* __restrict__ resid) {
    int tid = threadIdx.x;
    int wv = tid >> 6, l = tid & 63;
    int nTilesN = Nc >> 6;
    int bm = blockIdx.x / nTilesN, bn = blockIdx.x - bm * nTilesN;
    size_t row0 = (size_t)bm * 64;
    int col0 = bn * 64;

    const bf16_t* Ap = A + ((size_t)(row0 + wv * 16 + (l & 15))) * K + ((l >> 4) * 8);
    const bf16_t* Bbase = BT + (size_t)((l >> 4) * 8);

    f32x4 z = {0.f, 0.f, 0.f, 0.f};
    f32x4 acc0 = z, acc1 = z, acc2 = z, acc3 = z;

    for (int kk = 0; kk < K; kk += 32) {
        bf16x8 a = *(const bf16x8*)(Ap + kk);
        bf16x8 b0 = *(const bf16x8*)(Bbase + (size_t)(col0 + 0 * 16 + (l & 15)) * K + kk);
        bf16x8 b1 = *(const bf16x8*)(Bbase + (size_t)(col0 + 1 * 16 + (l & 15)) * K + kk);
        bf16x8 b2 = *(const bf16x8*)(Bbase + (size_t)(col0 + 2 * 16 + (l & 15)) * K + kk);
        bf16x8 b3 = *(const bf16x8*)(Bbase + (size_t)(col0 + 3 * 16 + (l & 15)) * K + kk);
        acc0 = __builtin_amdgcn_mfma_f32_16x16x32_bf16(a, b0, acc0, 0, 0, 0);
        acc1 = __builtin_amdgcn_mfma_f32_16x16x32_bf16(a, b1, acc1, 0, 0, 0);
        acc2 = __builtin_amdgcn_mfma_f32_16x16x32_bf16(a, b2, acc2, 0, 0, 0);
        acc3 = __builtin_amdgcn_mfma_f32_16x16x32_bf16(a, b3, acc3, 0, 0, 0);
    }

    // C/D layout: col = lane&15, row = (lane>>4)*4 + reg   [verified mapping]
    int crow0 = (int)row0 + wv * 16 + (l >> 4) * 4;
    int ccol_in = l & 15;
    f32x4 accs[4] = {acc0, acc1, acc2, acc3};
    #pragma unroll
    for (int ct = 0; ct < 4; ++ct) {
        int cc = col0 + ct * 16 + ccol_in;
        float bvl = bias[cc];
        #pragma unroll
        for (int i = 0; i < 4; ++i) {
            int rr = crow0 + i;
            float v = accs[ct][i] + bvl;
            if (EPI == 0) {
                outb[(size_t)rr * Nc + cc] = (bf16_t)v;
            } else if (EPI == 1) {
                float t = v + 0.044715f * v * v * v;
                float gl = 0.5f * v * (1.f + tanhf(0.7978845608028654f * t));
                outb[(size_t)rr * Nc + cc] = (bf16_t)gl;
            } else if (EPI == 2) {
                size_t o = (size_t)rr * Nc + cc;
                outf[o] = v + resid[o];
            } else {
                size_t o = (size_t)xrow_of(rr) * DIMC + cc;
                outf[o] = v + resid[o];
            }
        }
    }
}

// ---------------- windowed attention: one block per (window, head) ----------------
__global__ __launch_bounds__(256) void attn_kernel(const bf16_t* __restrict__ qkv,
                                                   const float* __restrict__ bias_table,
                                                   bf16_t* __restrict__ out) {
    __shared__ float qs[NTOK][33], ks[NTOK][33], vs[NTOK][33];
    __shared__ float S[NTOK][53];
    int head = blockIdx.x & 7;
    int wi = blockIdx.x >> 3;          // 0..2047
    int w64 = wi & 63;
    int wh = w64 >> 3, ww = w64 & 7;
    int tid = threadIdx.x;
    size_t rowbase = (size_t)wi * NTOK;

    for (int e = tid; e < NTOK * HD; e += 256) {
        int n = e >> 5, d = e & 31;
        size_t base = (rowbase + n) * 768 + head * HD + d;
        qs[n][d] = (float)qkv[base];
        ks[n][d] = (float)qkv[base + 256];
        vs[n][d] = (float)qkv[base + 512];
    }
    __syncthreads();

    for (int e = tid; e < NTOK * NTOK; e += 256) {
        int n = e / 49, m = e - n * 49;
        float s = 0.f;
        #pragma unroll
        for (int d = 0; d < HD; ++d) s += qs[n][d] * ks[m][d];
        s *= SCALE_QK;
        int i1 = n / 7, j1 = n - i1 * 7;
        int i2 = m / 7, j2 = m - i2 * 7;
        int bidx = (i1 - i2 + 6) + 13 * (j1 - j2 + 6);
        s += bias_table[bidx * 8 + head];
        // shifted-window mask: region ids in shifted-frame coords
        int hy1 = wh * 7 + i1, wy1 = ww * 7 + j1;
        int hy2 = wh * 7 + i2, wy2 = ww * 7 + j2;
        int rh1 = (hy1 < 49) ? 0 : ((hy1 < 53) ? 1 : 2);
        int rw1 = (wy1 < 49) ? 0 : ((wy1 < 53) ? 1 : 2);
        int rh2 = (hy2 < 49) ? 0 : ((hy2 < 53) ? 1 : 2);
        int rw2 = (wy2 < 49) ? 0 : ((wy2 < 53) ? 1 : 2);
        if ((rh1 * 3 + rw1) != (rh2 * 3 + rw2)) s -= 100.f;
        S[n][m] = s;
    }
    __syncthreads();

    if (tid < NTOK) {
        float mx = -1e30f;
        for (int m = 0; m < NTOK; ++m) mx = fmaxf(mx, S[tid][m]);
        float sum = 0.f;
        for (int m = 0; m < NTOK; ++m) {
            float e = __expf(S[tid][m] - mx);
            S[tid][m] = e;
            sum += e;
        }
        float inv = 1.f / sum;
        for (int m = 0; m < NTOK; ++m) S[tid][m] *= inv;
    }
    __syncthreads();

    for (int e = tid; e < NTOK * HD; e += 256) {
        int n = e >> 5, d = e & 31;
        float acc = 0.f;
        #pragma unroll
        for (int m = 0; m < NTOK; ++m) acc += S[n][m] * vs[m][d];
        out[(rowbase + n) * DIMC + head * HD + d] = (bf16_t)acc;
    }
}

extern "C" void kernel_launch(void* const* d_in, const int* in_sizes, int n_in,
                              void* d_out, int out_size, void* d_ws, size_t ws_size,
                              hipStream_t stream) {
    const float* x      = (const float*)d_in[0];
    const float* n1g    = (const float*)d_in[1];
    const float* n1b    = (const float*)d_in[2];
    const float* qkv_w  = (const float*)d_in[3];
    const float* qkv_b  = (const float*)d_in[4];
    const float* proj_w = (const float*)d_in[5];
    const float* proj_b = (const float*)d_in[6];
    const float* btab   = (const float*)d_in[7];
    const float* n2g    = (const float*)d_in[8];
    const float* n2b    = (const float*)d_in[9];
    const float* w1     = (const float*)d_in[10];
    const float* b1     = (const float*)d_in[11];
    const float* w2     = (const float*)d_in[12];
    const float* b2     = (const float*)d_in[13];

    char* ws = (char*)d_ws;
    // region A (205.5 MB): win [T][256]bf16 + qkv [T][768]bf16; later aliased by mlp1_out [T][1024]bf16
    bf16_t* win      = (bf16_t*)(ws);
    bf16_t* qkvbuf   = (bf16_t*)(ws + (size_t)T_TOK * 256 * 2);
    bf16_t* mlp1_buf = (bf16_t*)(ws);
    bf16_t* h2       = (bf16_t*)(ws + (size_t)T_TOK * 2048);
    char* wtp        = ws + (size_t)T_TOK * 2048 + (size_t)T_TOK * 512;
    bf16_t* wt_qkv   = (bf16_t*)wtp;               // [768][256]
    bf16_t* wt_proj  = wt_qkv + 768 * 256;         // [256][256]
    bf16_t* wt_mlp1  = wt_proj + 256 * 256;        // [1024][256]
    bf16_t* wt_mlp2  = wt_mlp1 + 1024 * 256;       // [256][1024]
    float* xmid      = (float*)d_out;              // x + attn branch lives in d_out

    // weights -> transposed bf16
    transpose_cast<<<768, 256, 0, stream>>>(qkv_w, wt_qkv, 256, 768);
    transpose_cast<<<256, 256, 0, stream>>>(proj_w, wt_proj, 256, 256);
    transpose_cast<<<1024, 256, 0, stream>>>(w1, wt_mlp1, 256, 1024);
    transpose_cast<<<1024, 256, 0, stream>>>(w2, wt_mlp2, 1024, 256);

    // LN1 + shift + window partition
    ln_kernel<1><<<T_TOK / 4, 256, 0, stream>>>(x, n1g, n1b, win);
    // QKV GEMM  [T,256] x [256,768]
    gemm_kernel<0><<<(T_TOK / 64) * (768 / 64), 256, 0, stream>>>(win, wt_qkv, qkv_b, 768, 256,
                                                                  qkvbuf, nullptr, nullptr);
    // attention per (window, head); writes attn_out into win's slot
    attn_kernel<<<2048 * HEADS, 256, 0, stream>>>(qkvbuf, btab, win);
    // proj GEMM + window reverse + unshift + residual -> xmid (= d_out)
    gemm_kernel<3><<<(T_TOK / 64) * (256 / 64), 256, 0, stream>>>(win, wt_proj, proj_b, 256, 256,
                                                                  nullptr, xmid, x);
    // LN2
    ln_kernel<0><<<T_TOK / 4, 256, 0, stream>>>(xmid, n2g, n2b, h2);
    // MLP1 + GELU  [T,256] x [256,1024]
    gemm_kernel<1><<<(T_TOK / 64) * (1024 / 64), 256, 0, stream>>>(h2, wt_mlp1, b1, 1024, 256,
                                                                   mlp1_buf, nullptr, nullptr);
    // MLP2 + residual  [T,1024] x [1024,256] -> d_out (in-place read-modify-write per element)
    gemm_kernel<2><<<(T_TOK / 64) * (256 / 64), 256, 0, stream>>>(mlp1_buf, wt_mlp2, b2, 256, 1024,
                                                                  nullptr, xmid, xmid);
}

// Round 2
// 799.722 us; speedup vs baseline: 2.2013x; 2.2013x over previous
//
#include <hip/hip_runtime.h>
#include <hip/hip_bf16.h>
#include <math.h>

typedef __bf16 bf16_t;
typedef __attribute__((ext_vector_type(8))) __bf16 bf16x8;
typedef __attribute__((ext_vector_type(4))) __bf16 bf16x4;
typedef __attribute__((ext_vector_type(4))) float f32x4;

#define T_TOK 100352      // 32 * 3136 tokens (= Bw*N = 2048*49)
#define DIMC 256
#define HEADS 8
#define HD 32
#define NTOK 49
#define SHIFT3 3
#define HH 56
#define SCALE_QK 0.17677669529663687f

// window-token row -> x row (shift maps source and dest to the SAME x row)
__device__ __forceinline__ int xrow_of(int rr) {
    int wi = rr / 49; int t = rr - wi * 49;
    int b = wi >> 6; int w64 = wi & 63;
    int wh = w64 >> 3, ww = w64 & 7;
    int i = t / 7, j = t - i * 7;
    int hy = wh * 7 + i, wy = ww * 7 + j;
    int hx = hy + SHIFT3; if (hx >= HH) hx -= HH;
    int wx = wy + SHIFT3; if (wx >= HH) wx -= HH;
    return b * (HH * HH) + hx * HH + wx;
}

// ---------------- weight transpose + bf16 cast:  W[K][Nc] -> WT[Nc][K] ----------------
__global__ __launch_bounds__(256) void transpose_cast(const float* __restrict__ W,
                                                      bf16_t* __restrict__ WT,
                                                      int K, int Nc) {
    int t = blockIdx.x * 256 + threadIdx.x;      // grid sized exactly K*Nc/256
    int k = t / Nc, c = t - k * Nc;
    WT[(size_t)c * K + k] = (bf16_t)W[t];
}

// ---------------- LayerNorm (+optional window gather) + bf16 cast ----------------
template <int MAP>
__global__ __launch_bounds__(256) void ln_kernel(const float* __restrict__ x,
                                                 const float* __restrict__ g,
                                                 const float* __restrict__ bsh,
                                                 bf16_t* __restrict__ out) {
    int wv = threadIdx.x >> 6, l = threadIdx.x & 63;
    int r = blockIdx.x * 4 + wv;
    int xr = MAP ? xrow_of(r) : r;
    float4 v = ((const float4*)(x + (size_t)xr * DIMC))[l];
    float s = v.x + v.y + v.z + v.w;
    float sq = v.x * v.x + v.y * v.y + v.z * v.z + v.w * v.w;
    #pragma unroll
    for (int off = 32; off; off >>= 1) {
        s += __shfl_down(s, off);
        sq += __shfl_down(sq, off);
    }
    s = __shfl(s, 0); sq = __shfl(sq, 0);
    float mean = s * (1.f / 256.f);
    float var = sq * (1.f / 256.f) - mean * mean;
    float rstd = rsqrtf(var + 1e-5f);
    float4 gv = ((const float4*)g)[l];
    float4 bv = ((const float4*)bsh)[l];
    bf16x4 o;
    o[0] = (bf16_t)((v.x - mean) * rstd * gv.x + bv.x);
    o[1] = (bf16_t)((v.y - mean) * rstd * gv.y + bv.y);
    o[2] = (bf16_t)((v.z - mean) * rstd * gv.z + bv.z);
    o[3] = (bf16_t)((v.w - mean) * rstd * gv.w + bv.w);
    *(bf16x4*)(out + (size_t)r * DIMC + l * 4) = o;
}

// ---------------- m97-style bf16 MFMA GEMM: C[M][Nc] = A[M][K] * BT[Nc][K]^T + bias ----
// 128x128 tile, BK=32, 256 thr (4 waves, 2x2), global_load_lds staging, 2-barrier loop.
// EPI: 0 = bias, store bf16 | 1 = bias+gelu, bf16 | 2 = bias + resid[r], f32 |
//      3 = bias + scatter to xrow_of(r) with resid, f32
template <int EPI>
__global__ __launch_bounds__(256) void gemm128(const bf16_t* __restrict__ A,
                                               const bf16_t* __restrict__ BT,
                                               const float* __restrict__ bias,
                                               int Nc, int K,
                                               bf16_t* __restrict__ outb,
                                               float* __restrict__ outf,
                                               const float* __restrict__ resid) {
    __shared__ bf16_t As[128 * 32];
    __shared__ bf16_t Bs[128 * 32];
    int tid = threadIdx.x;
    int wv = tid >> 6, l = tid & 63;
    int wr = wv >> 1, wc = wv & 1;
    int nTilesN = Nc >> 7;
    int bm = blockIdx.x / nTilesN, bn = blockIdx.x - bm * nTilesN;
    size_t row0 = (size_t)bm * 128;
    int col0 = bn * 128;

    const char* Abase = (const char*)(A + row0 * K);
    const char* Bbase = (const char*)(BT + (size_t)col0 * K);
    const size_t ldb = (size_t)K * 2;

    f32x4 acc[4][4] = {};
    const int lr = l & 15, lk = (l >> 4) * 8;
    const int aoff = (wr * 64 + lr) * 32 + lk;   // element offset into As
    const int boff = (wc * 64 + lr) * 32 + lk;

    // per-thread staging source coords (row = t>>2 of tile, 16B chunk (t&3))
    for (int kk = 0; kk < K; kk += 32) {
        #pragma unroll
        for (int it = 0; it < 2; ++it) {
            int t = tid + it * 256;
            int row = t >> 2, cb = (t & 3) * 16;
            __builtin_amdgcn_global_load_lds(
                (const __attribute__((address_space(1))) void*)(Abase + (size_t)row * ldb + (size_t)kk * 2 + cb),
                (__attribute__((address_space(3))) void*)((char*)As + t * 16), 16, 0, 0);
            __builtin_amdgcn_global_load_lds(
                (const __attribute__((address_space(1))) void*)(Bbase + (size_t)row * ldb + (size_t)kk * 2 + cb),
                (__attribute__((address_space(3))) void*)((char*)Bs + t * 16), 16, 0, 0);
        }
        __syncthreads();
        bf16x8 a[4], b[4];
        #pragma unroll
        for (int m = 0; m < 4; ++m) a[m] = *(const bf16x8*)(As + aoff + m * 16 * 32);
        #pragma unroll
        for (int n = 0; n < 4; ++n) b[n] = *(const bf16x8*)(Bs + boff + n * 16 * 32);
        #pragma unroll
        for (int m = 0; m < 4; ++m)
            #pragma unroll
            for (int n = 0; n < 4; ++n)
                acc[m][n] = __builtin_amdgcn_mfma_f32_16x16x32_bf16(a[m], b[n], acc[m][n], 0, 0, 0);
        __syncthreads();
    }

    // C/D layout: col = lane&15, row = (lane>>4)*4 + reg
    #pragma unroll
    for (int m = 0; m < 4; ++m) {
        #pragma unroll
        for (int i = 0; i < 4; ++i) {
            int rr = (int)row0 + wr * 64 + m * 16 + (l >> 4) * 4 + i;
            size_t orow = (EPI == 3) ? (size_t)xrow_of(rr) * DIMC : (size_t)rr * Nc;
            #pragma unroll
            for (int n = 0; n < 4; ++n) {
                int cc = col0 + wc * 64 + n * 16 + (l & 15);
                float v = acc[m][n][i] + bias[cc];
                if (EPI == 0) {
                    outb[(size_t)rr * Nc + cc] = (bf16_t)v;
                } else if (EPI == 1) {
                    float t = v + 0.044715f * v * v * v;
                    float gl = 0.5f * v * (1.f + tanhf(0.7978845608028654f * t));
                    outb[(size_t)rr * Nc + cc] = (bf16_t)gl;
                } else if (EPI == 2) {
                    size_t o = (size_t)rr * Nc + cc;
                    outf[o] = v + resid[o];
                } else {
                    size_t o = orow + cc;
                    outf[o] = v + resid[o];
                }
            }
        }
    }
}

// ---------------- windowed attention: one block per (window, head) ----------------
__global__ __launch_bounds__(256) void attn_kernel(const bf16_t* __restrict__ qkv,
                                                   const float* __restrict__ bias_table,
                                                   bf16_t* __restrict__ out) {
    __shared__ float qs[NTOK][33], ks[NTOK][33], vs[NTOK][33];
    __shared__ float S[NTOK][53];
    int head = blockIdx.x & 7;
    int wi = blockIdx.x >> 3;          // 0..2047
    int w64 = wi & 63;
    int wh = w64 >> 3, ww = w64 & 7;
    int tid = threadIdx.x;
    size_t rowbase = (size_t)wi * NTOK;

    for (int e = tid; e < NTOK * HD; e += 256) {
        int n = e >> 5, d = e & 31;
        size_t base = (rowbase + n) * 768 + head * HD + d;
        qs[n][d] = (float)qkv[base];
        ks[n][d] = (float)qkv[base + 256];
        vs[n][d] = (float)qkv[base + 512];
    }
    __syncthreads();

    for (int e = tid; e < NTOK * NTOK; e += 256) {
        int n = e / 49, m = e - n * 49;
        float s = 0.f;
        #pragma unroll
        for (int d = 0; d < HD; ++d) s += qs[n][d] * ks[m][d];
        s *= SCALE_QK;
        int i1 = n / 7, j1 = n - i1 * 7;
        int i2 = m / 7, j2 = m - i2 * 7;
        int bidx = (i1 - i2 + 6) + 13 * (j1 - j2 + 6);
        s += bias_table[bidx * 8 + head];
        int hy1 = wh * 7 + i1, wy1 = ww * 7 + j1;
        int hy2 = wh * 7 + i2, wy2 = ww * 7 + j2;
        int rh1 = (hy1 < 49) ? 0 : ((hy1 < 53) ? 1 : 2);
        int rw1 = (wy1 < 49) ? 0 : ((wy1 < 53) ? 1 : 2);
        int rh2 = (hy2 < 49) ? 0 : ((hy2 < 53) ? 1 : 2);
        int rw2 = (wy2 < 49) ? 0 : ((wy2 < 53) ? 1 : 2);
        if ((rh1 * 3 + rw1) != (rh2 * 3 + rw2)) s -= 100.f;
        S[n][m] = s;
    }
    __syncthreads();

    if (tid < NTOK) {
        float mx = -1e30f;
        for (int m = 0; m < NTOK; ++m) mx = fmaxf(mx, S[tid][m]);
        float sum = 0.f;
        for (int m = 0; m < NTOK; ++m) {
            float e = __expf(S[tid][m] - mx);
            S[tid][m] = e;
            sum += e;
        }
        float inv = 1.f / sum;
        for (int m = 0; m < NTOK; ++m) S[tid][m] *= inv;
    }
    __syncthreads();

    for (int e = tid; e < NTOK * HD; e += 256) {
        int n = e >> 5, d = e & 31;
        float acc = 0.f;
        #pragma unroll
        for (int m = 0; m < NTOK; ++m) acc += S[n][m] * vs[m][d];
        out[(rowbase + n) * DIMC + head * HD + d] = (bf16_t)acc;
    }
}

extern "C" void kernel_launch(void* const* d_in, const int* in_sizes, int n_in,
                              void* d_out, int out_size, void* d_ws, size_t ws_size,
                              hipStream_t stream) {
    const float* x      = (const float*)d_in[0];
    const float* n1g    = (const float*)d_in[1];
    const float* n1b    = (const float*)d_in[2];
    const float* qkv_w  = (const float*)d_in[3];
    const float* qkv_b  = (const float*)d_in[4];
    const float* proj_w = (const float*)d_in[5];
    const float* proj_b = (const float*)d_in[6];
    const float* btab   = (const float*)d_in[7];
    const float* n2g    = (const float*)d_in[8];
    const float* n2b    = (const float*)d_in[9];
    const float* w1     = (const float*)d_in[10];
    const float* b1     = (const float*)d_in[11];
    const float* w2     = (const float*)d_in[12];
    const float* b2     = (const float*)d_in[13];

    char* ws = (char*)d_ws;
    bf16_t* win      = (bf16_t*)(ws);
    bf16_t* qkvbuf   = (bf16_t*)(ws + (size_t)T_TOK * 256 * 2);
    bf16_t* mlp1_buf = (bf16_t*)(ws);
    bf16_t* h2       = (bf16_t*)(ws + (size_t)T_TOK * 2048);
    char* wtp        = ws + (size_t)T_TOK * 2048 + (size_t)T_TOK * 512;
    bf16_t* wt_qkv   = (bf16_t*)wtp;               // [768][256]
    bf16_t* wt_proj  = wt_qkv + 768 * 256;         // [256][256]
    bf16_t* wt_mlp1  = wt_proj + 256 * 256;        // [1024][256]
    bf16_t* wt_mlp2  = wt_mlp1 + 1024 * 256;       // [256][1024]
    float* xmid      = (float*)d_out;

    transpose_cast<<<768, 256, 0, stream>>>(qkv_w, wt_qkv, 256, 768);
    transpose_cast<<<256, 256, 0, stream>>>(proj_w, wt_proj, 256, 256);
    transpose_cast<<<1024, 256, 0, stream>>>(w1, wt_mlp1, 256, 1024);
    transpose_cast<<<1024, 256, 0, stream>>>(w2, wt_mlp2, 1024, 256);

    ln_kernel<1><<<T_TOK / 4, 256, 0, stream>>>(x, n1g, n1b, win);
    // QKV GEMM  [T,256] x [256,768]
    gemm128<0><<<(T_TOK / 128) * (768 / 128), 256, 0, stream>>>(win, wt_qkv, qkv_b, 768, 256,
                                                                qkvbuf, nullptr, nullptr);
    attn_kernel<<<2048 * HEADS, 256, 0, stream>>>(qkvbuf, btab, win);
    // proj GEMM + window reverse + unshift + residual -> xmid (= d_out)
    gemm128<3><<<(T_TOK / 128) * (256 / 128), 256, 0, stream>>>(win, wt_proj, proj_b, 256, 256,
                                                                nullptr, xmid, x);
    ln_kernel<0><<<T_TOK / 4, 256, 0, stream>>>(xmid, n2g, n2b, h2);
    // MLP1 + GELU  [T,256] x [256,1024]
    gemm128<1><<<(T_TOK / 128) * (1024 / 128), 256, 0, stream>>>(h2, wt_mlp1, b1, 1024, 256,
                                                                 mlp1_buf, nullptr, nullptr);
    // MLP2 + residual  [T,1024] x [1024,256] -> d_out
    gemm128<2><<<(T_TOK / 128) * (256 / 128), 256, 0, stream>>>(mlp1_buf, wt_mlp2, b2, 256, 1024,
                                                                nullptr, xmid, xmid);
}

// Round 3
// 599.617 us; speedup vs baseline: 2.9360x; 1.3337x over previous
//
#include <hip/hip_runtime.h>
#include <hip/hip_bf16.h>
#include <math.h>

typedef __bf16 bf16_t;
typedef __attribute__((ext_vector_type(8))) __bf16 bf16x8;
typedef __attribute__((ext_vector_type(4))) __bf16 bf16x4;
typedef __attribute__((ext_vector_type(4))) float f32x4;

#define T_TOK 100352      // 32 * 3136 tokens (= Bw*N = 2048*49)
#define DIMC 256
#define HEADS 8
#define HD 32
#define NTOK 49
#define SHIFT3 3
#define HH 56
#define SCALE_QK 0.17677669529663687f

// window-token row -> x row (shift maps source and dest to the SAME x row)
__device__ __forceinline__ int xrow_of(int rr) {
    int wi = rr / 49; int t = rr - wi * 49;
    int b = wi >> 6; int w64 = wi & 63;
    int wh = w64 >> 3, ww = w64 & 7;
    int i = t / 7, j = t - i * 7;
    int hy = wh * 7 + i, wy = ww * 7 + j;
    int hx = hy + SHIFT3; if (hx >= HH) hx -= HH;
    int wx = wy + SHIFT3; if (wx >= HH) wx -= HH;
    return b * (HH * HH) + hx * HH + wx;
}

// ---------------- weight transpose + bf16 cast:  W[K][Nc] -> WT[Nc][K] ----------------
__global__ __launch_bounds__(256) void transpose_cast(const float* __restrict__ W,
                                                      bf16_t* __restrict__ WT,
                                                      int K, int Nc) {
    int t = blockIdx.x * 256 + threadIdx.x;
    int k = t / Nc, c = t - k * Nc;
    WT[(size_t)c * K + k] = (bf16_t)W[t];
}

// ---------------- LayerNorm (+optional window gather) + bf16 cast ----------------
template <int MAP>
__global__ __launch_bounds__(256) void ln_kernel(const float* __restrict__ x,
                                                 const float* __restrict__ g,
                                                 const float* __restrict__ bsh,
                                                 bf16_t* __restrict__ out) {
    int wv = threadIdx.x >> 6, l = threadIdx.x & 63;
    int r = blockIdx.x * 4 + wv;
    int xr = MAP ? xrow_of(r) : r;
    float4 v = ((const float4*)(x + (size_t)xr * DIMC))[l];
    float s = v.x + v.y + v.z + v.w;
    float sq = v.x * v.x + v.y * v.y + v.z * v.z + v.w * v.w;
    #pragma unroll
    for (int off = 32; off; off >>= 1) {
        s += __shfl_down(s, off);
        sq += __shfl_down(sq, off);
    }
    s = __shfl(s, 0); sq = __shfl(sq, 0);
    float mean = s * (1.f / 256.f);
    float var = sq * (1.f / 256.f) - mean * mean;
    float rstd = rsqrtf(var + 1e-5f);
    float4 gv = ((const float4*)g)[l];
    float4 bv = ((const float4*)bsh)[l];
    bf16x4 o;
    o[0] = (bf16_t)((v.x - mean) * rstd * gv.x + bv.x);
    o[1] = (bf16_t)((v.y - mean) * rstd * gv.y + bv.y);
    o[2] = (bf16_t)((v.z - mean) * rstd * gv.z + bv.z);
    o[3] = (bf16_t)((v.w - mean) * rstd * gv.w + bv.w);
    *(bf16x4*)(out + (size_t)r * DIMC + l * 4) = o;
}

// ---------------- m97-style bf16 MFMA GEMM (128x128 tile, BK=32) ----------------
template <int EPI>
__global__ __launch_bounds__(256) void gemm128(const bf16_t* __restrict__ A,
                                               const bf16_t* __restrict__ BT,
                                               const float* __restrict__ bias,
                                               int Nc, int K,
                                               bf16_t* __restrict__ outb,
                                               float* __restrict__ outf,
                                               const float* __restrict__ resid) {
    __shared__ bf16_t As[128 * 32];
    __shared__ bf16_t Bs[128 * 32];
    int tid = threadIdx.x;
    int wv = tid >> 6, l = tid & 63;
    int wr = wv >> 1, wc = wv & 1;
    int nTilesN = Nc >> 7;
    int bm = blockIdx.x / nTilesN, bn = blockIdx.x - bm * nTilesN;
    size_t row0 = (size_t)bm * 128;
    int col0 = bn * 128;

    const char* Abase = (const char*)(A + row0 * K);
    const char* Bbase = (const char*)(BT + (size_t)col0 * K);
    const size_t ldb = (size_t)K * 2;

    f32x4 acc[4][4] = {};
    const int lr = l & 15, lk = (l >> 4) * 8;
    const int aoff = (wr * 64 + lr) * 32 + lk;
    const int boff = (wc * 64 + lr) * 32 + lk;

    for (int kk = 0; kk < K; kk += 32) {
        #pragma unroll
        for (int it = 0; it < 2; ++it) {
            int t = tid + it * 256;
            int row = t >> 2, cb = (t & 3) * 16;
            __builtin_amdgcn_global_load_lds(
                (const __attribute__((address_space(1))) void*)(Abase + (size_t)row * ldb + (size_t)kk * 2 + cb),
                (__attribute__((address_space(3))) void*)((char*)As + t * 16), 16, 0, 0);
            __builtin_amdgcn_global_load_lds(
                (const __attribute__((address_space(1))) void*)(Bbase + (size_t)row * ldb + (size_t)kk * 2 + cb),
                (__attribute__((address_space(3))) void*)((char*)Bs + t * 16), 16, 0, 0);
        }
        __syncthreads();
        bf16x8 a[4], b[4];
        #pragma unroll
        for (int m = 0; m < 4; ++m) a[m] = *(const bf16x8*)(As + aoff + m * 16 * 32);
        #pragma unroll
        for (int n = 0; n < 4; ++n) b[n] = *(const bf16x8*)(Bs + boff + n * 16 * 32);
        #pragma unroll
        for (int m = 0; m < 4; ++m)
            #pragma unroll
            for (int n = 0; n < 4; ++n)
                acc[m][n] = __builtin_amdgcn_mfma_f32_16x16x32_bf16(a[m], b[n], acc[m][n], 0, 0, 0);
        __syncthreads();
    }

    #pragma unroll
    for (int m = 0; m < 4; ++m) {
        #pragma unroll
        for (int i = 0; i < 4; ++i) {
            int rr = (int)row0 + wr * 64 + m * 16 + (l >> 4) * 4 + i;
            size_t orow = (EPI == 3) ? (size_t)xrow_of(rr) * DIMC : (size_t)rr * Nc;
            #pragma unroll
            for (int n = 0; n < 4; ++n) {
                int cc = col0 + wc * 64 + n * 16 + (l & 15);
                float v = acc[m][n][i] + bias[cc];
                if (EPI == 0) {
                    outb[(size_t)rr * Nc + cc] = (bf16_t)v;
                } else if (EPI == 1) {
                    float t = v + 0.044715f * v * v * v;
                    float gl = 0.5f * v * (1.f + tanhf(0.7978845608028654f * t));
                    outb[(size_t)rr * Nc + cc] = (bf16_t)gl;
                } else if (EPI == 2) {
                    size_t o = (size_t)rr * Nc + cc;
                    outf[o] = v + resid[o];
                } else {
                    size_t o = orow + cc;
                    outf[o] = v + resid[o];
                }
            }
        }
    }
}

// ---------------- MFMA windowed attention ----------------
// One block (4 waves) per (window, head-half). Each wave owns one head; no inter-wave sync.
// Per-wave LDS (12800B): Q[64][32] swz | K[64][32] swz | Vt[32][72] ; P[64][64] swz aliases Q+K.
__global__ __launch_bounds__(256) void attn_mfma(const bf16_t* __restrict__ qkv,
                                                 const float* __restrict__ bt,
                                                 bf16_t* __restrict__ out) {
    __shared__ __align__(16) char lds[4][12800];
    int wv = threadIdx.x >> 6, l = threadIdx.x & 63;
    int head = ((blockIdx.x & 1) << 2) | wv;
    int wi = blockIdx.x >> 1;
    char* W = lds[wv];
    bf16_t* Vt = (bf16_t*)(W + 8192);          // [32][72]
    size_t rowbase = (size_t)wi * NTOK;
    const bf16_t* src = qkv + rowbase * 768 + head * HD;

    int w64 = wi & 63;
    int wh = w64 >> 3, ww = w64 & 7;
    bool lastH = (wh == 7), lastW = (ww == 7);
    bool masked = lastH || lastW;

    // ---- stage Q, K (rows < 49; padding rows left as-is, masked later) ----
    #pragma unroll
    for (int it = 0; it < 4; ++it) {
        int t = l + it * 64;
        int r = t >> 2, g = t & 3;
        if (r < NTOK) {
            bf16x8 qv = *(const bf16x8*)(src + (size_t)r * 768 + g * 8);
            bf16x8 kv = *(const bf16x8*)(src + (size_t)r * 768 + 256 + g * 8);
            int sa = (r * 64 + g * 16) ^ ((r & 7) << 4);
            *(bf16x8*)(W + sa) = qv;
            *(bf16x8*)(W + 4096 + sa) = kv;
        }
    }
    // ---- stage V transposed: Vt[d][m] (cols m>=49 zero-filled) ----
    #pragma unroll
    for (int it = 0; it < 4; ++it) {
        int t = l + it * 64;
        int m = t >> 2, dc = t & 3;
        if (m < NTOK) {
            bf16x8 vv = *(const bf16x8*)(src + (size_t)m * 768 + 512 + dc * 8);
            #pragma unroll
            for (int j = 0; j < 8; ++j) Vt[(dc * 8 + j) * 72 + m] = vv[j];
        } else {
            #pragma unroll
            for (int j = 0; j < 8; ++j) Vt[(dc * 8 + j) * 72 + m] = (bf16_t)0.f;
        }
    }

    int lr = l & 15, g4 = l >> 4;

    // ---- QK^T: S[mt][nt], row n = mt*16+g4*4+i (q), col m = nt*16+lr (k) ----
    bf16x8 a[4], b[4];
    #pragma unroll
    for (int mt = 0; mt < 4; ++mt) {
        int r = mt * 16 + lr;
        int sa = (r * 64 + g4 * 16) ^ ((r & 7) << 4);
        a[mt] = *(const bf16x8*)(W + sa);
        b[mt] = *(const bf16x8*)(W + 4096 + sa);
    }
    f32x4 z = {0.f, 0.f, 0.f, 0.f};
    f32x4 S[4][4];
    #pragma unroll
    for (int mt = 0; mt < 4; ++mt)
        #pragma unroll
        for (int nt = 0; nt < 4; ++nt)
            S[mt][nt] = __builtin_amdgcn_mfma_f32_16x16x32_bf16(a[mt], b[nt], z, 0, 0, 0);

    // column (k-token) indices per lane
    int i2[4], j2[4], reg2[4];
    #pragma unroll
    for (int nt = 0; nt < 4; ++nt) {
        int cm = nt * 16 + lr;
        i2[nt] = (cm * 147) >> 10;
        j2[nt] = cm - i2[nt] * 7;
        int rh = lastH ? ((i2[nt] < 4) ? 1 : 2) : 0;
        int rw = lastW ? ((j2[nt] < 4) ? 1 : 2) : 0;
        reg2[nt] = rh * 3 + rw;
    }

    // ---- bias + mask + row softmax + write P to LDS (aliases Q+K) ----
    #pragma unroll
    for (int mt = 0; mt < 4; ++mt) {
        #pragma unroll
        for (int i = 0; i < 4; ++i) {
            int rn = mt * 16 + g4 * 4 + i;
            bool rowok = rn < NTOK;
            int i1 = (rn * 147) >> 10, j1 = rn - i1 * 7;
            int rh1 = lastH ? ((i1 < 4) ? 1 : 2) : 0;
            int rw1 = lastW ? ((j1 < 4) ? 1 : 2) : 0;
            int reg1 = rh1 * 3 + rw1;
            float sv[4];
            #pragma unroll
            for (int nt = 0; nt < 4; ++nt) {
                int cm = nt * 16 + lr;
                float s;
                if (rowok && cm < NTOK) {
                    s = S[mt][nt][i] * SCALE_QK;
                    s += bt[((i1 - i2[nt] + 6) + 13 * (j1 - j2[nt] + 6)) * 8 + head];
                    if (masked && (reg1 != reg2[nt])) s -= 100.f;
                } else {
                    s = -1e30f;
                }
                sv[nt] = s;
            }
            float mx = fmaxf(fmaxf(sv[0], sv[1]), fmaxf(sv[2], sv[3]));
            mx = fmaxf(mx, __shfl_xor(mx, 1));
            mx = fmaxf(mx, __shfl_xor(mx, 2));
            mx = fmaxf(mx, __shfl_xor(mx, 4));
            mx = fmaxf(mx, __shfl_xor(mx, 8));
            float e[4];
            float sum = 0.f;
            #pragma unroll
            for (int nt = 0; nt < 4; ++nt) { e[nt] = __expf(sv[nt] - mx); sum += e[nt]; }
            sum += __shfl_xor(sum, 1);
            sum += __shfl_xor(sum, 2);
            sum += __shfl_xor(sum, 4);
            sum += __shfl_xor(sum, 8);
            float inv = 1.f / sum;
            #pragma unroll
            for (int nt = 0; nt < 4; ++nt) {
                int cm = nt * 16 + lr;
                int pa = (rn * 128 + cm * 2) ^ ((rn & 7) << 4);
                *(bf16_t*)(W + pa) = (bf16_t)(e[nt] * inv);
            }
        }
    }

    // ---- PV: out[n][d] = sum_m P[n][m] * Vt[d][m] ----
    f32x4 o[4][2] = {};
    #pragma unroll
    for (int ks = 0; ks < 2; ++ks) {
        bf16x8 pa[4], vb[2];
        #pragma unroll
        for (int mt = 0; mt < 4; ++mt) {
            int r = mt * 16 + lr;
            int ad = (r * 128 + ks * 64 + g4 * 16) ^ ((r & 7) << 4);
            pa[mt] = *(const bf16x8*)(W + ad);
        }
        #pragma unroll
        for (int dt = 0; dt < 2; ++dt) {
            int d = dt * 16 + lr;
            vb[dt] = *(const bf16x8*)((char*)Vt + d * 144 + ks * 64 + g4 * 16);
        }
        #pragma unroll
        for (int mt = 0; mt < 4; ++mt)
            #pragma unroll
            for (int dt = 0; dt < 2; ++dt)
                o[mt][dt] = __builtin_amdgcn_mfma_f32_16x16x32_bf16(pa[mt], vb[dt], o[mt][dt], 0, 0, 0);
    }

    // ---- store out rows < 49 ----
    #pragma unroll
    for (int mt = 0; mt < 4; ++mt) {
        #pragma unroll
        for (int i = 0; i < 4; ++i) {
            int n = mt * 16 + g4 * 4 + i;
            if (n < NTOK) {
                #pragma unroll
                for (int dt = 0; dt < 2; ++dt) {
                    out[(rowbase + n) * DIMC + head * HD + dt * 16 + lr] = (bf16_t)o[mt][dt][i];
                }
            }
        }
    }
}

extern "C" void kernel_launch(void* const* d_in, const int* in_sizes, int n_in,
                              void* d_out, int out_size, void* d_ws, size_t ws_size,
                              hipStream_t stream) {
    const float* x      = (const float*)d_in[0];
    const float* n1g    = (const float*)d_in[1];
    const float* n1b    = (const float*)d_in[2];
    const float* qkv_w  = (const float*)d_in[3];
    const float* qkv_b  = (const float*)d_in[4];
    const float* proj_w = (const float*)d_in[5];
    const float* proj_b = (const float*)d_in[6];
    const float* btab   = (const float*)d_in[7];
    const float* n2g    = (const float*)d_in[8];
    const float* n2b    = (const float*)d_in[9];
    const float* w1     = (const float*)d_in[10];
    const float* b1     = (const float*)d_in[11];
    const float* w2     = (const float*)d_in[12];
    const float* b2     = (const float*)d_in[13];

    char* ws = (char*)d_ws;
    bf16_t* win      = (bf16_t*)(ws);
    bf16_t* qkvbuf   = (bf16_t*)(ws + (size_t)T_TOK * 256 * 2);
    bf16_t* mlp1_buf = (bf16_t*)(ws);
    bf16_t* h2       = (bf16_t*)(ws + (size_t)T_TOK * 2048);
    char* wtp        = ws + (size_t)T_TOK * 2048 + (size_t)T_TOK * 512;
    bf16_t* wt_qkv   = (bf16_t*)wtp;               // [768][256]
    bf16_t* wt_proj  = wt_qkv + 768 * 256;         // [256][256]
    bf16_t* wt_mlp1  = wt_proj + 256 * 256;        // [1024][256]
    bf16_t* wt_mlp2  = wt_mlp1 + 1024 * 256;       // [256][1024]
    float* xmid      = (float*)d_out;

    transpose_cast<<<768, 256, 0, stream>>>(qkv_w, wt_qkv, 256, 768);
    transpose_cast<<<256, 256, 0, stream>>>(proj_w, wt_proj, 256, 256);
    transpose_cast<<<1024, 256, 0, stream>>>(w1, wt_mlp1, 256, 1024);
    transpose_cast<<<1024, 256, 0, stream>>>(w2, wt_mlp2, 1024, 256);

    ln_kernel<1><<<T_TOK / 4, 256, 0, stream>>>(x, n1g, n1b, win);
    // QKV GEMM  [T,256] x [256,768]
    gemm128<0><<<(T_TOK / 128) * (768 / 128), 256, 0, stream>>>(win, wt_qkv, qkv_b, 768, 256,
                                                                qkvbuf, nullptr, nullptr);
    // MFMA attention: 2 blocks per window (4 heads each)
    attn_mfma<<<2048 * 2, 256, 0, stream>>>(qkvbuf, btab, win);
    // proj GEMM + window reverse + unshift + residual -> xmid (= d_out)
    gemm128<3><<<(T_TOK / 128) * (256 / 128), 256, 0, stream>>>(win, wt_proj, proj_b, 256, 256,
                                                                nullptr, xmid, x);
    ln_kernel<0><<<T_TOK / 4, 256, 0, stream>>>(xmid, n2g, n2b, h2);
    // MLP1 + GELU  [T,256] x [256,1024]
    gemm128<1><<<(T_TOK / 128) * (1024 / 128), 256, 0, stream>>>(h2, wt_mlp1, b1, 1024, 256,
                                                                 mlp1_buf, nullptr, nullptr);
    // MLP2 + residual  [T,1024] x [1024,256] -> d_out
    gemm128<2><<<(T_TOK / 128) * (256 / 128), 256, 0, stream>>>(mlp1_buf, wt_mlp2, b2, 256, 1024,
                                                                nullptr, xmid, xmid);
}